// Round 2
// baseline (1334.608 us; speedup 1.0000x reference)
//
#include <hip/hip_runtime.h>

// =====================================================================
// GraphAutoEncoder forward (all fp32):
//   h1 = relu(x @ W1^T + b1)          [N,256]->[N,128]
//   h2 = relu(h1 @ W2^T + b2)         [N,128]->[N,64]
//   h3 = relu(GCN(h2; Wg1,bg1))       [N,64]
//   h4 = relu(GCN(h3; Wg2,bg2))       [N,64]
//   h5 = relu(h4 @ Wd1^T + bd1)       [N,64]->[N,128]
//   out = sigmoid(h5 @ Wd2^T + bd2)   [N,128]->[N,256]
// GCN(h;W,b) = scatter_{dst}( (hW^T)[src] * dinv[src]*w*dinv[dst] )
//              + (hW^T)[i]*dinv[i]^2 (self loop) + b
// deg[i] = sum_{e: dst=i} w[e] + 1 (self-loop), dinv = rsqrt(deg)
// NOTE: harness materializes integer inputs as int32 (edge_index -> const int*).
// =====================================================================

// ---------------- GEMM: C[N,M] = act(A[N,K] @ W[M,K]^T + b) ----------
// block = 256 threads = 4 waves; tile = 64 nodes; wave fb computes
// features [fb*JM, (fb+1)*JM). A staged in LDS (stride 65 -> 2-way bank
// aliasing = free). Weight addresses wave-uniform -> scalar/broadcast.
template <int K, int M, int ACT, bool BIAS>  // ACT: 0 none, 1 relu, 2 sigmoid
__global__ __launch_bounds__(256) void gemm_act(const float* __restrict__ A,
                                                const float* __restrict__ W,
                                                const float* __restrict__ bias,
                                                float* __restrict__ C, int N) {
    constexpr int JM = M / 4;
    constexpr int KC = 64;
    __shared__ float sA[64 * (KC + 1)];

    const int tid  = threadIdx.x;
    const int lane = tid & 63;
    const int fb   = __builtin_amdgcn_readfirstlane(tid >> 6);  // wave id, uniform
    const long long nodeBase = (long long)blockIdx.x * 64;
    const int node = (int)nodeBase + lane;

    float acc[JM];
#pragma unroll
    for (int j = 0; j < JM; ++j) acc[j] = 0.f;

    for (int kc = 0; kc < K; kc += KC) {
        __syncthreads();
        // stage A[nodeBase..+63][kc..kc+63]: 1024 float4 by 256 threads
#pragma unroll
        for (int i = 0; i < 4; ++i) {
            int idx = tid + 256 * i;  // 0..1023
            int n   = idx >> 4;       // node-in-tile
            int k4  = idx & 15;       // float4 within 64-float chunk
            float4 v = make_float4(0.f, 0.f, 0.f, 0.f);
            long long gn = nodeBase + n;
            if (gn < N) v = *(const float4*)(A + gn * (long long)K + kc + k4 * 4);
            float* dst = sA + n * (KC + 1) + k4 * 4;
            dst[0] = v.x; dst[1] = v.y; dst[2] = v.z; dst[3] = v.w;
        }
        __syncthreads();
        const float* sa = sA + lane * (KC + 1);
        for (int k4 = 0; k4 < KC / 4; ++k4) {
            float a0 = sa[k4 * 4 + 0];
            float a1 = sa[k4 * 4 + 1];
            float a2 = sa[k4 * 4 + 2];
            float a3 = sa[k4 * 4 + 3];
#pragma unroll
            for (int j = 0; j < JM; ++j) {
                const float* wp = W + (long long)(fb * JM + j) * K + kc + k4 * 4;
                float4 w = *(const float4*)wp;
                acc[j] += a0 * w.x + a1 * w.y + a2 * w.z + a3 * w.w;
            }
        }
    }

    if (node < N) {
        float* cp = C + (long long)node * M + fb * JM;
#pragma unroll
        for (int j4 = 0; j4 < JM / 4; ++j4) {
            float4 v;
            float t[4];
#pragma unroll
            for (int c = 0; c < 4; ++c) {
                float x = acc[j4 * 4 + c];
                if constexpr (BIAS) x += bias[fb * JM + j4 * 4 + c];
                if constexpr (ACT == 1) x = fmaxf(x, 0.f);
                if constexpr (ACT == 2) x = 1.f / (1.f + __expf(-x));
                t[c] = x;
            }
            v.x = t[0]; v.y = t[1]; v.z = t[2]; v.w = t[3];
            *(float4*)(cp + j4 * 4) = v;
        }
    }
}

// ---------------- degree / dinv ----------------
__global__ __launch_bounds__(256) void fill_zero(float* __restrict__ p, int n) {
    int i = blockIdx.x * 256 + threadIdx.x;
    if (i < n) p[i] = 0.f;
}

__global__ __launch_bounds__(256) void deg_edges(const int* __restrict__ ei,
                                                 const float* __restrict__ w,
                                                 float* __restrict__ deg, int E) {
    int e = blockIdx.x * 256 + threadIdx.x;
    if (e < E) {
        int d = ei[E + e];  // dst row
        atomicAdd(deg + d, w[e]);
    }
}

__global__ __launch_bounds__(256) void dinv_k(const float* __restrict__ deg,
                                              float* __restrict__ dinv, int n) {
    int i = blockIdx.x * 256 + threadIdx.x;
    if (i < n) {
        float d = deg[i] + 1.0f;  // + self-loop weight
        dinv[i] = (d > 0.f) ? rsqrtf(fmaxf(d, 1e-12f)) : 0.f;
    }
}

// ---------------- GCN aggregation ----------------
// a[i][:] = t[i][:] * dinv[i]^2    (self-loop message)
__global__ __launch_bounds__(256) void scatter_init(const float4* __restrict__ t,
                                                    const float* __restrict__ dinv,
                                                    float4* __restrict__ a, int n16) {
    int i = blockIdx.x * 256 + threadIdx.x;  // over N*16 float4 (64 feats)
    if (i < n16) {
        float di = dinv[i >> 4];
        float s  = di * di;
        float4 v = t[i];
        a[i] = make_float4(v.x * s, v.y * s, v.z * s, v.w * s);
    }
}

// one wave per edge (looped): lane = feature 0..63
__global__ __launch_bounds__(256) void scatter_edges(const int* __restrict__ ei,
                                                     const float* __restrict__ w,
                                                     const float* __restrict__ dinv,
                                                     const float* __restrict__ t,
                                                     float* __restrict__ a, int E) {
    const int lane = threadIdx.x & 63;
    const int wv   = threadIdx.x >> 6;
    long long e = (long long)blockIdx.x * 4 + wv;
    const long long stride = (long long)gridDim.x * 4;
    for (; e < E; e += stride) {
        int s = ei[e];
        int d = ei[E + e];
        float norm = dinv[s] * w[e] * dinv[d];
        float val  = t[(long long)s * 64 + lane] * norm;
        atomicAdd(a + (long long)d * 64 + lane, val);
    }
}

// h[i][f] = relu(a[i][f] + b[f])   (64 feats = 16 float4)
__global__ __launch_bounds__(256) void bias_relu64(const float4* __restrict__ a,
                                                   const float4* __restrict__ b,
                                                   float4* __restrict__ h, int n16) {
    int i = blockIdx.x * 256 + threadIdx.x;
    if (i < n16) {
        float4 bb = b[i & 15];
        float4 v  = a[i];
        h[i] = make_float4(fmaxf(v.x + bb.x, 0.f), fmaxf(v.y + bb.y, 0.f),
                           fmaxf(v.z + bb.z, 0.f), fmaxf(v.w + bb.w, 0.f));
    }
}

// =====================================================================
extern "C" void kernel_launch(void* const* d_in, const int* in_sizes, int n_in,
                              void* d_out, int out_size, void* d_ws, size_t ws_size,
                              hipStream_t stream) {
    const float* x      = (const float*)d_in[0];
    const int*   ei     = (const int*)d_in[1];    // int32 per harness contract
    const float* ew     = (const float*)d_in[2];
    const float* enc1_w = (const float*)d_in[3];
    const float* enc1_b = (const float*)d_in[4];
    const float* enc2_w = (const float*)d_in[5];
    const float* enc2_b = (const float*)d_in[6];
    const float* gcn1_w = (const float*)d_in[7];
    const float* gcn1_b = (const float*)d_in[8];
    const float* gcn2_w = (const float*)d_in[9];
    const float* gcn2_b = (const float*)d_in[10];
    const float* dec1_w = (const float*)d_in[11];
    const float* dec1_b = (const float*)d_in[12];
    const float* dec2_w = (const float*)d_in[13];
    const float* dec2_b = (const float*)d_in[14];

    const int N = in_sizes[0] / 256;   // 50000
    const int E = in_sizes[2];         // 1600000

    // workspace layout (aliased; total N*194 floats ~= 38.8 MB):
    //   bufA [N*128]: h1 (encoder), later reused as {bufC,bufD}, later h5
    //   bufB [N*64] : h2 / h3 / h4
    //   deg,dinv [N each]
    float* ws   = (float*)d_ws;
    float* bufA = ws;
    float* bufB = bufA + (size_t)N * 128;
    float* bufC = bufA;                       // t = hW^T  (aliases h1, dead)
    float* bufD = bufA + (size_t)N * 64;      // aggregation accumulator
    float* deg  = bufB + (size_t)N * 64;
    float* dinv = deg + N;

    const int gemmGrid = (N + 63) / 64;       // 782
    const int n16      = N * 16;              // float4 count for [N,64]

    // encoder
    gemm_act<256, 128, 1, true><<<gemmGrid, 256, 0, stream>>>(x, enc1_w, enc1_b, bufA, N);
    gemm_act<128, 64, 1, true><<<gemmGrid, 256, 0, stream>>>(bufA, enc2_w, enc2_b, bufB, N);

    // degree / dinv (shared by both GCN layers)
    fill_zero<<<(N + 255) / 256, 256, 0, stream>>>(deg, N);
    deg_edges<<<(E + 255) / 256, 256, 0, stream>>>(ei, ew, deg, E);
    dinv_k<<<(N + 255) / 256, 256, 0, stream>>>(deg, dinv, N);

    // GCN layer 1
    gemm_act<64, 64, 0, false><<<gemmGrid, 256, 0, stream>>>(bufB, gcn1_w, nullptr, bufC, N);
    scatter_init<<<(n16 + 255) / 256, 256, 0, stream>>>((const float4*)bufC, dinv,
                                                        (float4*)bufD, n16);
    scatter_edges<<<16384, 256, 0, stream>>>(ei, ew, dinv, bufC, bufD, E);
    bias_relu64<<<(n16 + 255) / 256, 256, 0, stream>>>((const float4*)bufD,
                                                       (const float4*)gcn1_b,
                                                       (float4*)bufB, n16);

    // GCN layer 2
    gemm_act<64, 64, 0, false><<<gemmGrid, 256, 0, stream>>>(bufB, gcn2_w, nullptr, bufC, N);
    scatter_init<<<(n16 + 255) / 256, 256, 0, stream>>>((const float4*)bufC, dinv,
                                                        (float4*)bufD, n16);
    scatter_edges<<<16384, 256, 0, stream>>>(ei, ew, dinv, bufC, bufD, E);
    bias_relu64<<<(n16 + 255) / 256, 256, 0, stream>>>((const float4*)bufD,
                                                       (const float4*)gcn2_b,
                                                       (float4*)bufB, n16);

    // decoder
    gemm_act<64, 128, 1, true><<<gemmGrid, 256, 0, stream>>>(bufB, dec1_w, dec1_b, bufA, N);
    gemm_act<128, 256, 2, true><<<gemmGrid, 256, 0, stream>>>(bufA, dec2_w, dec2_b,
                                                              (float*)d_out, N);
}

// Round 3
// 869.254 us; speedup vs baseline: 1.5353x; 1.5353x over previous
//
#include <hip/hip_runtime.h>

// =====================================================================
// GraphAutoEncoder forward (all fp32). GCN aggregation is done via a
// per-launch CSR build (edges grouped by dst) + gather-sum — no fp32
// atomics (R2 profile: scatter_edges wrote 400 MB of atomic traffic to
// HBM per layer at 335 us; gather keeps the 12.8 MB table in L2/L3).
// =====================================================================

// ---------------- GEMM: C[N,M] = act(A[N,K] @ W[M,K]^T + b) ----------
template <int K, int M, int ACT, bool BIAS>  // ACT: 0 none, 1 relu, 2 sigmoid
__global__ __launch_bounds__(256) void gemm_act(const float* __restrict__ A,
                                                const float* __restrict__ W,
                                                const float* __restrict__ bias,
                                                float* __restrict__ C, int N) {
    constexpr int JM = M / 4;
    constexpr int KC = 64;
    __shared__ float sA[64 * (KC + 1)];

    const int tid  = threadIdx.x;
    const int lane = tid & 63;
    const int fb   = __builtin_amdgcn_readfirstlane(tid >> 6);  // wave id, uniform
    const long long nodeBase = (long long)blockIdx.x * 64;
    const int node = (int)nodeBase + lane;

    float acc[JM];
#pragma unroll
    for (int j = 0; j < JM; ++j) acc[j] = 0.f;

    for (int kc = 0; kc < K; kc += KC) {
        __syncthreads();
#pragma unroll
        for (int i = 0; i < 4; ++i) {
            int idx = tid + 256 * i;  // 0..1023
            int n   = idx >> 4;
            int k4  = idx & 15;
            float4 v = make_float4(0.f, 0.f, 0.f, 0.f);
            long long gn = nodeBase + n;
            if (gn < N) v = *(const float4*)(A + gn * (long long)K + kc + k4 * 4);
            float* dst = sA + n * (KC + 1) + k4 * 4;
            dst[0] = v.x; dst[1] = v.y; dst[2] = v.z; dst[3] = v.w;
        }
        __syncthreads();
        const float* sa = sA + lane * (KC + 1);
        for (int k4 = 0; k4 < KC / 4; ++k4) {
            float a0 = sa[k4 * 4 + 0];
            float a1 = sa[k4 * 4 + 1];
            float a2 = sa[k4 * 4 + 2];
            float a3 = sa[k4 * 4 + 3];
#pragma unroll
            for (int j = 0; j < JM; ++j) {
                const float* wp = W + (long long)(fb * JM + j) * K + kc + k4 * 4;
                float4 w = *(const float4*)wp;
                acc[j] += a0 * w.x + a1 * w.y + a2 * w.z + a3 * w.w;
            }
        }
    }

    if (node < N) {
        float* cp = C + (long long)node * M + fb * JM;
#pragma unroll
        for (int j4 = 0; j4 < JM / 4; ++j4) {
            float4 v;
            float t[4];
#pragma unroll
            for (int c = 0; c < 4; ++c) {
                float x = acc[j4 * 4 + c];
                if constexpr (BIAS) x += bias[fb * JM + j4 * 4 + c];
                if constexpr (ACT == 1) x = fmaxf(x, 0.f);
                if constexpr (ACT == 2) x = 1.f / (1.f + __expf(-x));
                t[c] = x;
            }
            v.x = t[0]; v.y = t[1]; v.z = t[2]; v.w = t[3];
            *(float4*)(cp + j4 * 4) = v;
        }
    }
}

// ---------------- CSR build ----------------
// zero deg[N] (float) and cnt[N] (int)
__global__ __launch_bounds__(256) void zero_deg_cnt(float* __restrict__ deg,
                                                    int* __restrict__ cnt, int n) {
    int i = blockIdx.x * 256 + threadIdx.x;
    if (i < n) { deg[i] = 0.f; cnt[i] = 0; }
}

__global__ __launch_bounds__(256) void hist_k(const int* __restrict__ ei,
                                              const float* __restrict__ w,
                                              float* __restrict__ deg,
                                              int* __restrict__ cnt, int E) {
    int e = blockIdx.x * 256 + threadIdx.x;
    if (e < E) {
        int d = ei[E + e];
        atomicAdd(deg + d, w[e]);
        atomicAdd(cnt + d, 1);
    }
}

__global__ __launch_bounds__(256) void dinv_k(const float* __restrict__ deg,
                                              float* __restrict__ dinv, int n) {
    int i = blockIdx.x * 256 + threadIdx.x;
    if (i < n) {
        float d = deg[i] + 1.0f;  // + self-loop weight
        dinv[i] = rsqrtf(fmaxf(d, 1e-12f));
    }
}

// block-level exclusive scan of cnt -> row (partial), block sums -> bs
__global__ __launch_bounds__(256) void scan_block(const int* __restrict__ cnt,
                                                  int* __restrict__ row,
                                                  int* __restrict__ bs, int n) {
    __shared__ int s[256];
    int i = blockIdx.x * 256 + threadIdx.x;
    int c = (i < n) ? cnt[i] : 0;
    s[threadIdx.x] = c;
    __syncthreads();
    for (int off = 1; off < 256; off <<= 1) {
        int v = (threadIdx.x >= off) ? s[threadIdx.x - off] : 0;
        __syncthreads();
        s[threadIdx.x] += v;
        __syncthreads();
    }
    if (i < n) row[i] = s[threadIdx.x] - c;  // exclusive within block
    if (threadIdx.x == 255) bs[blockIdx.x] = s[255];
}

// exclusive scan of block sums in-place (nb <= 256)
__global__ __launch_bounds__(256) void scan_tops(int* __restrict__ bs, int nb) {
    __shared__ int s[256];
    int t = threadIdx.x;
    int v = (t < nb) ? bs[t] : 0;
    s[t] = v;
    __syncthreads();
    for (int off = 1; off < 256; off <<= 1) {
        int u = (t >= off) ? s[t - off] : 0;
        __syncthreads();
        s[t] += u;
        __syncthreads();
    }
    if (t < nb) bs[t] = s[t] - v;
}

__global__ __launch_bounds__(256) void scan_add(int* __restrict__ row,
                                                const int* __restrict__ bs,
                                                int n, int E) {
    int i = blockIdx.x * 256 + threadIdx.x;
    if (i < n) row[i] += bs[blockIdx.x];
    if (i == 0) row[n] = E;
}

__global__ __launch_bounds__(256) void zero_int(int* __restrict__ p, int n) {
    int i = blockIdx.x * 256 + threadIdx.x;
    if (i < n) p[i] = 0;
}

// place each edge at row[dst] + fill[dst]++ ; payload = {src, norm}
__global__ __launch_bounds__(256) void csr_scatter(const int* __restrict__ ei,
                                                   const float* __restrict__ w,
                                                   const float* __restrict__ dinv,
                                                   const int* __restrict__ row,
                                                   int* __restrict__ fill,
                                                   int2* __restrict__ sn, int E) {
    int e = blockIdx.x * 256 + threadIdx.x;
    if (e < E) {
        int s = ei[e];
        int d = ei[E + e];
        int pos = row[d] + atomicAdd(fill + d, 1);
        float nr = dinv[s] * w[e] * dinv[d];
        sn[pos] = make_int2(s, __float_as_int(nr));
    }
}

// ---------------- fused GCN aggregation ----------------
// one wave per dst node (lane = feature): register accumulation, no atomics.
// out[i] = relu( sum_e t[src_e]*norm_e + t[i]*dinv[i]^2 + b )
__global__ __launch_bounds__(256) void gcn_agg(const float* __restrict__ t,
                                               const int2* __restrict__ sn,
                                               const int* __restrict__ row,
                                               const float* __restrict__ dinv,
                                               const float* __restrict__ bias,
                                               float* __restrict__ out, int N) {
    const int lane = threadIdx.x & 63;
    int i = __builtin_amdgcn_readfirstlane((int)(blockIdx.x * 4) + (threadIdx.x >> 6));
    if (i >= N) return;
    float di  = dinv[i];
    float acc = t[(size_t)i * 64 + lane] * di * di;  // self-loop
    int p  = row[i];
    int pe = row[i + 1];
    for (; p + 4 <= pe; p += 4) {
        int2 v0 = sn[p];
        int2 v1 = sn[p + 1];
        int2 v2 = sn[p + 2];
        int2 v3 = sn[p + 3];
        acc += t[(size_t)v0.x * 64 + lane] * __int_as_float(v0.y);
        acc += t[(size_t)v1.x * 64 + lane] * __int_as_float(v1.y);
        acc += t[(size_t)v2.x * 64 + lane] * __int_as_float(v2.y);
        acc += t[(size_t)v3.x * 64 + lane] * __int_as_float(v3.y);
    }
    for (; p < pe; ++p) {
        int2 v = sn[p];
        acc += t[(size_t)v.x * 64 + lane] * __int_as_float(v.y);
    }
    acc += bias[lane];
    acc = fmaxf(acc, 0.f);
    out[(size_t)i * 64 + lane] = acc;
}

// =====================================================================
extern "C" void kernel_launch(void* const* d_in, const int* in_sizes, int n_in,
                              void* d_out, int out_size, void* d_ws, size_t ws_size,
                              hipStream_t stream) {
    const float* x      = (const float*)d_in[0];
    const int*   ei     = (const int*)d_in[1];   // int32 per harness contract
    const float* ew     = (const float*)d_in[2];
    const float* enc1_w = (const float*)d_in[3];
    const float* enc1_b = (const float*)d_in[4];
    const float* enc2_w = (const float*)d_in[5];
    const float* enc2_b = (const float*)d_in[6];
    const float* gcn1_w = (const float*)d_in[7];
    const float* gcn1_b = (const float*)d_in[8];
    const float* gcn2_w = (const float*)d_in[9];
    const float* gcn2_b = (const float*)d_in[10];
    const float* dec1_w = (const float*)d_in[11];
    const float* dec1_b = (const float*)d_in[12];
    const float* dec2_w = (const float*)d_in[13];
    const float* dec2_b = (const float*)d_in[14];

    const int N = in_sizes[0] / 256;   // 50000
    const int E = in_sizes[2];         // 1600000

    // workspace layout (~39.5 MB):
    //  bufA [N*128 floats]: h1 (encoder) -> then {sn[E] int2 | bufC[N*64]} -> h5
    //  bufB [N*64]: h2/h3/h4
    //  deg[N], dinv[N], row[N+1] int, cnt[N] int, bs[256] int
    float* ws   = (float*)d_ws;
    float* bufA = ws;
    int2*  sn   = (int2*)bufA;                       // E int2 = 2E words
    float* bufC = bufA + (size_t)2 * E;              // N*64 words (2E == N*64)
    float* bufB = bufA + (size_t)N * 128;
    float* deg  = bufB + (size_t)N * 64;
    float* dinv = deg + N;
    int*   row  = (int*)(dinv + N);                  // N+1
    int*   cnt  = row + (N + 1);                     // N
    int*   bs   = cnt + N;                           // scan block sums

    const int gemmGrid = (N + 63) / 64;              // 782
    const int nBlkN    = (N + 255) / 256;            // 196 (fits scan_tops' 256)
    const int nBlkE    = (E + 255) / 256;

    // encoder
    gemm_act<256, 128, 1, true><<<gemmGrid, 256, 0, stream>>>(x, enc1_w, enc1_b, bufA, N);
    gemm_act<128, 64, 1, true><<<gemmGrid, 256, 0, stream>>>(bufA, enc2_w, enc2_b, bufB, N);

    // CSR build (shared by both GCN layers); bufA dead from here until dec1
    zero_deg_cnt<<<nBlkN, 256, 0, stream>>>(deg, cnt, N);
    hist_k<<<nBlkE, 256, 0, stream>>>(ei, ew, deg, cnt, E);
    dinv_k<<<nBlkN, 256, 0, stream>>>(deg, dinv, N);
    scan_block<<<nBlkN, 256, 0, stream>>>(cnt, row, bs, N);
    scan_tops<<<1, 256, 0, stream>>>(bs, nBlkN);
    scan_add<<<nBlkN, 256, 0, stream>>>(row, bs, N, E);
    zero_int<<<nBlkN, 256, 0, stream>>>(cnt, N);
    csr_scatter<<<nBlkE, 256, 0, stream>>>(ei, ew, dinv, row, cnt, sn, E);

    // GCN layer 1
    gemm_act<64, 64, 0, false><<<gemmGrid, 256, 0, stream>>>(bufB, gcn1_w, nullptr, bufC, N);
    gcn_agg<<<(N + 3) / 4, 256, 0, stream>>>(bufC, sn, row, dinv, gcn1_b, bufB, N);

    // GCN layer 2
    gemm_act<64, 64, 0, false><<<gemmGrid, 256, 0, stream>>>(bufB, gcn2_w, nullptr, bufC, N);
    gcn_agg<<<(N + 3) / 4, 256, 0, stream>>>(bufC, sn, row, dinv, gcn2_b, bufB, N);

    // decoder
    gemm_act<64, 128, 1, true><<<gemmGrid, 256, 0, stream>>>(bufB, dec1_w, dec1_b, bufA, N);
    gemm_act<128, 256, 2, true><<<gemmGrid, 256, 0, stream>>>(bufA, dec2_w, dec2_b,
                                                              (float*)d_out, N);
}

// Round 4
// 678.919 us; speedup vs baseline: 1.9658x; 1.2803x over previous
//
#include <hip/hip_runtime.h>

// =====================================================================
// GraphAutoEncoder forward (all fp32). GCN via CSR build + gather (R2).
// R3: GEMM rewritten as register-tiled outer-product (old version was
// latency-bound at VALUBusy=15%: 4-deep dependent FMA chains + scalar
// weight loads). New: 128-node x MT-feat block tile, A/W staged in LDS
// transposed, 8xTM register tile per thread -> 64 independent FMAs per
// 16 LDS floats.
// =====================================================================

// ---------------- GEMM: C[:,foff:foff+MT] = act(A @ W^T + b) ---------
// K: inner dim, MT: feature tile (per blockIdx.y), M: full row stride.
template <int K, int MT, int M, int ACT, bool BIAS>  // ACT: 0 none,1 relu,2 sigmoid
__global__ __launch_bounds__(256) void gemm_rt(const float* __restrict__ A,
                                               const float* __restrict__ W,
                                               const float* __restrict__ bias,
                                               float* __restrict__ C, int N) {
    constexpr int KC = 32;
    constexpr int TM = MT / 16;   // feats per thread (4 or 8)
    constexpr int TN = 8;         // nodes per thread (stride 16)
    __shared__ float As[KC][128 + 4];
    __shared__ float Ws[KC][MT + 4];

    const int tid  = threadIdx.x;
    const int tx   = tid & 15;    // node group: nodes tx, tx+16, ..., tx+112
    const int ty   = tid >> 4;    // feat group: feats ty*TM .. ty*TM+TM
    const int nodeBase = blockIdx.x * 128;
    const int foff     = blockIdx.y * MT;

    float acc[TN][TM];
#pragma unroll
    for (int i = 0; i < TN; ++i)
#pragma unroll
        for (int j = 0; j < TM; ++j) acc[i][j] = 0.f;

    for (int kc = 0; kc < K; kc += KC) {
        __syncthreads();
        // stage A[nodeBase..+128][kc..kc+32] transposed -> As[k][n]
#pragma unroll
        for (int i = 0; i < 4; ++i) {
            int f  = tid + 256 * i;   // 0..1023
            int n  = f >> 3;          // 0..127
            int k4 = f & 7;           // 0..7
            int gn = nodeBase + n;
            float4 v = make_float4(0.f, 0.f, 0.f, 0.f);
            if (gn < N) v = *(const float4*)(A + (size_t)gn * K + kc + k4 * 4);
            As[k4 * 4 + 0][n] = v.x;
            As[k4 * 4 + 1][n] = v.y;
            As[k4 * 4 + 2][n] = v.z;
            As[k4 * 4 + 3][n] = v.w;
        }
        // stage W[foff..foff+MT][kc..kc+32] transposed -> Ws[k][m]
#pragma unroll
        for (int i = 0; i < MT / 32; ++i) {
            int f  = tid + 256 * i;   // 0..MT*8-1
            int m  = f >> 3;          // 0..MT-1
            int k4 = f & 7;
            float4 v = *(const float4*)(W + (size_t)(foff + m) * K + kc + k4 * 4);
            Ws[k4 * 4 + 0][m] = v.x;
            Ws[k4 * 4 + 1][m] = v.y;
            Ws[k4 * 4 + 2][m] = v.z;
            Ws[k4 * 4 + 3][m] = v.w;
        }
        __syncthreads();
#pragma unroll 4
        for (int k = 0; k < KC; ++k) {
            float a[TN];
            float w[TM];
#pragma unroll
            for (int i = 0; i < TN; ++i) a[i] = As[k][tx + 16 * i];  // b32, conflict-free
#pragma unroll
            for (int j4 = 0; j4 < TM / 4; ++j4) {
                float4 wv = *(const float4*)&Ws[k][ty * TM + j4 * 4];  // broadcast
                w[j4 * 4 + 0] = wv.x; w[j4 * 4 + 1] = wv.y;
                w[j4 * 4 + 2] = wv.z; w[j4 * 4 + 3] = wv.w;
            }
#pragma unroll
            for (int i = 0; i < TN; ++i)
#pragma unroll
                for (int j = 0; j < TM; ++j) acc[i][j] = fmaf(a[i], w[j], acc[i][j]);
        }
    }

    // epilogue
#pragma unroll
    for (int i = 0; i < TN; ++i) {
        int node = nodeBase + tx + 16 * i;
        if (node < N) {
            float* cp = C + (size_t)node * M + foff + ty * TM;
#pragma unroll
            for (int j4 = 0; j4 < TM / 4; ++j4) {
                float t[4];
#pragma unroll
                for (int c = 0; c < 4; ++c) {
                    float x = acc[i][j4 * 4 + c];
                    if constexpr (BIAS) x += bias[foff + ty * TM + j4 * 4 + c];
                    if constexpr (ACT == 1) x = fmaxf(x, 0.f);
                    if constexpr (ACT == 2) x = 1.f / (1.f + __expf(-x));
                    t[c] = x;
                }
                float4 v; v.x = t[0]; v.y = t[1]; v.z = t[2]; v.w = t[3];
                *(float4*)(cp + j4 * 4) = v;
            }
        }
    }
}

// ---------------- CSR build ----------------
__global__ __launch_bounds__(256) void zero_deg_cnt(float* __restrict__ deg,
                                                    int* __restrict__ cnt, int n) {
    int i = blockIdx.x * 256 + threadIdx.x;
    if (i < n) { deg[i] = 0.f; cnt[i] = 0; }
}

__global__ __launch_bounds__(256) void hist_k(const int* __restrict__ ei,
                                              const float* __restrict__ w,
                                              float* __restrict__ deg,
                                              int* __restrict__ cnt, int E) {
    int e = blockIdx.x * 256 + threadIdx.x;
    if (e < E) {
        int d = ei[E + e];
        atomicAdd(deg + d, w[e]);
        atomicAdd(cnt + d, 1);
    }
}

__global__ __launch_bounds__(256) void dinv_k(const float* __restrict__ deg,
                                              float* __restrict__ dinv, int n) {
    int i = blockIdx.x * 256 + threadIdx.x;
    if (i < n) {
        float d = deg[i] + 1.0f;  // + self-loop weight
        dinv[i] = rsqrtf(fmaxf(d, 1e-12f));
    }
}

__global__ __launch_bounds__(256) void scan_block(const int* __restrict__ cnt,
                                                  int* __restrict__ row,
                                                  int* __restrict__ bs, int n) {
    __shared__ int s[256];
    int i = blockIdx.x * 256 + threadIdx.x;
    int c = (i < n) ? cnt[i] : 0;
    s[threadIdx.x] = c;
    __syncthreads();
    for (int off = 1; off < 256; off <<= 1) {
        int v = (threadIdx.x >= off) ? s[threadIdx.x - off] : 0;
        __syncthreads();
        s[threadIdx.x] += v;
        __syncthreads();
    }
    if (i < n) row[i] = s[threadIdx.x] - c;
    if (threadIdx.x == 255) bs[blockIdx.x] = s[255];
}

__global__ __launch_bounds__(256) void scan_tops(int* __restrict__ bs, int nb) {
    __shared__ int s[256];
    int t = threadIdx.x;
    int v = (t < nb) ? bs[t] : 0;
    s[t] = v;
    __syncthreads();
    for (int off = 1; off < 256; off <<= 1) {
        int u = (t >= off) ? s[t - off] : 0;
        __syncthreads();
        s[t] += u;
        __syncthreads();
    }
    if (t < nb) bs[t] = s[t] - v;
}

__global__ __launch_bounds__(256) void scan_add(int* __restrict__ row,
                                                const int* __restrict__ bs,
                                                int n, int E) {
    int i = blockIdx.x * 256 + threadIdx.x;
    if (i < n) row[i] += bs[blockIdx.x];
    if (i == 0) row[n] = E;
}

__global__ __launch_bounds__(256) void zero_int(int* __restrict__ p, int n) {
    int i = blockIdx.x * 256 + threadIdx.x;
    if (i < n) p[i] = 0;
}

__global__ __launch_bounds__(256) void csr_scatter(const int* __restrict__ ei,
                                                   const float* __restrict__ w,
                                                   const float* __restrict__ dinv,
                                                   const int* __restrict__ row,
                                                   int* __restrict__ fill,
                                                   int2* __restrict__ sn, int E) {
    int e = blockIdx.x * 256 + threadIdx.x;
    if (e < E) {
        int s = ei[e];
        int d = ei[E + e];
        int pos = row[d] + atomicAdd(fill + d, 1);
        float nr = dinv[s] * w[e] * dinv[d];
        sn[pos] = make_int2(s, __float_as_int(nr));
    }
}

// ---------------- fused GCN aggregation (gather, no atomics) ---------
__global__ __launch_bounds__(256) void gcn_agg(const float* __restrict__ t,
                                               const int2* __restrict__ sn,
                                               const int* __restrict__ row,
                                               const float* __restrict__ dinv,
                                               const float* __restrict__ bias,
                                               float* __restrict__ out, int N) {
    const int lane = threadIdx.x & 63;
    int i = __builtin_amdgcn_readfirstlane((int)(blockIdx.x * 4) + (threadIdx.x >> 6));
    if (i >= N) return;
    float di  = dinv[i];
    float acc = t[(size_t)i * 64 + lane] * di * di;  // self-loop
    int p  = row[i];
    int pe = row[i + 1];
    for (; p + 4 <= pe; p += 4) {
        int2 v0 = sn[p];
        int2 v1 = sn[p + 1];
        int2 v2 = sn[p + 2];
        int2 v3 = sn[p + 3];
        acc += t[(size_t)v0.x * 64 + lane] * __int_as_float(v0.y);
        acc += t[(size_t)v1.x * 64 + lane] * __int_as_float(v1.y);
        acc += t[(size_t)v2.x * 64 + lane] * __int_as_float(v2.y);
        acc += t[(size_t)v3.x * 64 + lane] * __int_as_float(v3.y);
    }
    for (; p < pe; ++p) {
        int2 v = sn[p];
        acc += t[(size_t)v.x * 64 + lane] * __int_as_float(v.y);
    }
    acc += bias[lane];
    acc = fmaxf(acc, 0.f);
    out[(size_t)i * 64 + lane] = acc;
}

// =====================================================================
extern "C" void kernel_launch(void* const* d_in, const int* in_sizes, int n_in,
                              void* d_out, int out_size, void* d_ws, size_t ws_size,
                              hipStream_t stream) {
    const float* x      = (const float*)d_in[0];
    const int*   ei     = (const int*)d_in[1];   // int32 per harness contract
    const float* ew     = (const float*)d_in[2];
    const float* enc1_w = (const float*)d_in[3];
    const float* enc1_b = (const float*)d_in[4];
    const float* enc2_w = (const float*)d_in[5];
    const float* enc2_b = (const float*)d_in[6];
    const float* gcn1_w = (const float*)d_in[7];
    const float* gcn1_b = (const float*)d_in[8];
    const float* gcn2_w = (const float*)d_in[9];
    const float* gcn2_b = (const float*)d_in[10];
    const float* dec1_w = (const float*)d_in[11];
    const float* dec1_b = (const float*)d_in[12];
    const float* dec2_w = (const float*)d_in[13];
    const float* dec2_b = (const float*)d_in[14];

    const int N = in_sizes[0] / 256;   // 50000
    const int E = in_sizes[2];         // 1600000

    // workspace (~39.5 MB):
    //  bufA [N*128]: h1 -> {sn[E] int2 | bufC[N*64]} -> h5
    //  bufB [N*64]: h2/h3/h4 ; deg/dinv [N] ; row[N+1], cnt[N], bs int
    float* ws   = (float*)d_ws;
    float* bufA = ws;
    int2*  sn   = (int2*)bufA;                 // 2E floats
    float* bufC = bufA + (size_t)2 * E;        // N*64 floats (2E == N*64)
    float* bufB = bufA + (size_t)N * 128;
    float* deg  = bufB + (size_t)N * 64;
    float* dinv = deg + N;
    int*   row  = (int*)(dinv + N);
    int*   cnt  = row + (N + 1);
    int*   bs   = cnt + N;

    const int gemmGrid = (N + 127) / 128;      // 391
    const int nBlkN    = (N + 255) / 256;      // 196
    const int nBlkE    = (E + 255) / 256;

    // encoder
    gemm_rt<256, 128, 128, 1, true><<<dim3(gemmGrid, 1), 256, 0, stream>>>(
        x, enc1_w, enc1_b, bufA, N);
    gemm_rt<128, 64, 64, 1, true><<<dim3(gemmGrid, 1), 256, 0, stream>>>(
        bufA, enc2_w, enc2_b, bufB, N);

    // CSR build (shared by both GCN layers); bufA dead until dec1
    zero_deg_cnt<<<nBlkN, 256, 0, stream>>>(deg, cnt, N);
    hist_k<<<nBlkE, 256, 0, stream>>>(ei, ew, deg, cnt, E);
    dinv_k<<<nBlkN, 256, 0, stream>>>(deg, dinv, N);
    scan_block<<<nBlkN, 256, 0, stream>>>(cnt, row, bs, N);
    scan_tops<<<1, 256, 0, stream>>>(bs, nBlkN);
    scan_add<<<nBlkN, 256, 0, stream>>>(row, bs, N, E);
    zero_int<<<nBlkN, 256, 0, stream>>>(cnt, N);
    csr_scatter<<<nBlkE, 256, 0, stream>>>(ei, ew, dinv, row, cnt, sn, E);

    // GCN layer 1
    gemm_rt<64, 64, 64, 0, false><<<dim3(gemmGrid, 1), 256, 0, stream>>>(
        bufB, gcn1_w, nullptr, bufC, N);
    gcn_agg<<<(N + 3) / 4, 256, 0, stream>>>(bufC, sn, row, dinv, gcn1_b, bufB, N);

    // GCN layer 2
    gemm_rt<64, 64, 64, 0, false><<<dim3(gemmGrid, 1), 256, 0, stream>>>(
        bufB, gcn2_w, nullptr, bufC, N);
    gcn_agg<<<(N + 3) / 4, 256, 0, stream>>>(bufC, sn, row, dinv, gcn2_b, bufB, N);

    // decoder
    gemm_rt<64, 128, 128, 1, true><<<dim3(gemmGrid, 1), 256, 0, stream>>>(
        bufB, dec1_w, dec1_b, bufA, N);
    gemm_rt<128, 128, 256, 2, true><<<dim3(gemmGrid, 2), 256, 0, stream>>>(
        bufA, dec2_w, dec2_b, (float*)d_out, N);
}

// Round 5
// 618.657 us; speedup vs baseline: 2.1573x; 1.0974x over previous
//
#include <hip/hip_runtime.h>

// =====================================================================
// GraphAutoEncoder forward (all fp32). GCN via CSR build + gather.
// R3: register-tiled fp32 GEMM (old was latency-bound, VALUBusy 15%).
// R4->R5: histogram atomics were contention-bound (20 atomics/ns vs 300
// achievable): drop the float deg histogram (deg now = segmented sum
// over built CSR), privatize cnt/fill counters 8-way (r = blockIdx&7).
// Payload = (src, dinv[src]*w); dinv[dst] factored into gcn_agg.
// =====================================================================

// ---------------- GEMM: C[:,foff:foff+MT] = act(A @ W^T + b) ---------
template <int K, int MT, int M, int ACT, bool BIAS>  // ACT: 0 none,1 relu,2 sigmoid
__global__ __launch_bounds__(256) void gemm_rt(const float* __restrict__ A,
                                               const float* __restrict__ W,
                                               const float* __restrict__ bias,
                                               float* __restrict__ C, int N) {
    constexpr int KC = 32;
    constexpr int TM = MT / 16;   // feats per thread
    constexpr int TN = 8;         // nodes per thread (stride 16)
    __shared__ float As[KC][128 + 4];
    __shared__ float Ws[KC][MT + 4];

    const int tid  = threadIdx.x;
    const int tx   = tid & 15;
    const int ty   = tid >> 4;
    const int nodeBase = blockIdx.x * 128;
    const int foff     = blockIdx.y * MT;

    float acc[TN][TM];
#pragma unroll
    for (int i = 0; i < TN; ++i)
#pragma unroll
        for (int j = 0; j < TM; ++j) acc[i][j] = 0.f;

    for (int kc = 0; kc < K; kc += KC) {
        __syncthreads();
#pragma unroll
        for (int i = 0; i < 4; ++i) {
            int f  = tid + 256 * i;   // 0..1023
            int n  = f >> 3;
            int k4 = f & 7;
            int gn = nodeBase + n;
            float4 v = make_float4(0.f, 0.f, 0.f, 0.f);
            if (gn < N) v = *(const float4*)(A + (size_t)gn * K + kc + k4 * 4);
            As[k4 * 4 + 0][n] = v.x;
            As[k4 * 4 + 1][n] = v.y;
            As[k4 * 4 + 2][n] = v.z;
            As[k4 * 4 + 3][n] = v.w;
        }
#pragma unroll
        for (int i = 0; i < MT / 32; ++i) {
            int f  = tid + 256 * i;
            int m  = f >> 3;
            int k4 = f & 7;
            float4 v = *(const float4*)(W + (size_t)(foff + m) * K + kc + k4 * 4);
            Ws[k4 * 4 + 0][m] = v.x;
            Ws[k4 * 4 + 1][m] = v.y;
            Ws[k4 * 4 + 2][m] = v.z;
            Ws[k4 * 4 + 3][m] = v.w;
        }
        __syncthreads();
#pragma unroll 4
        for (int k = 0; k < KC; ++k) {
            float a[TN];
            float w[TM];
#pragma unroll
            for (int i = 0; i < TN; ++i) a[i] = As[k][tx + 16 * i];
#pragma unroll
            for (int j4 = 0; j4 < TM / 4; ++j4) {
                float4 wv = *(const float4*)&Ws[k][ty * TM + j4 * 4];
                w[j4 * 4 + 0] = wv.x; w[j4 * 4 + 1] = wv.y;
                w[j4 * 4 + 2] = wv.z; w[j4 * 4 + 3] = wv.w;
            }
#pragma unroll
            for (int i = 0; i < TN; ++i)
#pragma unroll
                for (int j = 0; j < TM; ++j) acc[i][j] = fmaf(a[i], w[j], acc[i][j]);
        }
    }

#pragma unroll
    for (int i = 0; i < TN; ++i) {
        int node = nodeBase + tx + 16 * i;
        if (node < N) {
            float* cp = C + (size_t)node * M + foff + ty * TM;
#pragma unroll
            for (int j4 = 0; j4 < TM / 4; ++j4) {
                float t[4];
#pragma unroll
                for (int c = 0; c < 4; ++c) {
                    float x = acc[i][j4 * 4 + c];
                    if constexpr (BIAS) x += bias[foff + ty * TM + j4 * 4 + c];
                    if constexpr (ACT == 1) x = fmaxf(x, 0.f);
                    if constexpr (ACT == 2) x = 1.f / (1.f + __expf(-x));
                    t[c] = x;
                }
                float4 v; v.x = t[0]; v.y = t[1]; v.z = t[2]; v.w = t[3];
                *(float4*)(cp + j4 * 4) = v;
            }
        }
    }
}

// ---------------- CSR build (8-way privatized counters) --------------
constexpr int REP = 8;

__global__ __launch_bounds__(256) void zero_int(int* __restrict__ p, int n) {
    int i = blockIdx.x * 256 + threadIdx.x;
    if (i < n) p[i] = 0;
}

// count edges per dst into replica r = blockIdx & 7
__global__ __launch_bounds__(256) void hist_k(const int* __restrict__ ei,
                                              int* __restrict__ cntR,
                                              int N, int E) {
    int e = blockIdx.x * 256 + threadIdx.x;
    if (e < E) {
        int d = ei[E + e];
        int r = blockIdx.x & (REP - 1);
        atomicAdd(cntR + r * N + d, 1);
    }
}

// block-level exclusive scan of (sum over replicas) -> row, block sums -> bs
__global__ __launch_bounds__(256) void scan_block(const int* __restrict__ cntR,
                                                  int* __restrict__ row,
                                                  int* __restrict__ bs, int n) {
    __shared__ int s[256];
    int i = blockIdx.x * 256 + threadIdx.x;
    int c = 0;
    if (i < n) {
#pragma unroll
        for (int r = 0; r < REP; ++r) c += cntR[r * n + i];
    }
    s[threadIdx.x] = c;
    __syncthreads();
    for (int off = 1; off < 256; off <<= 1) {
        int v = (threadIdx.x >= off) ? s[threadIdx.x - off] : 0;
        __syncthreads();
        s[threadIdx.x] += v;
        __syncthreads();
    }
    if (i < n) row[i] = s[threadIdx.x] - c;
    if (threadIdx.x == 255) bs[blockIdx.x] = s[255];
}

__global__ __launch_bounds__(256) void scan_tops(int* __restrict__ bs, int nb) {
    __shared__ int s[256];
    int t = threadIdx.x;
    int v = (t < nb) ? bs[t] : 0;
    s[t] = v;
    __syncthreads();
    for (int off = 1; off < 256; off <<= 1) {
        int u = (t >= off) ? s[t - off] : 0;
        __syncthreads();
        s[t] += u;
        __syncthreads();
    }
    if (t < nb) bs[t] = s[t] - v;
}

__global__ __launch_bounds__(256) void scan_add(int* __restrict__ row,
                                                const int* __restrict__ bs,
                                                int n, int E) {
    int i = blockIdx.x * 256 + threadIdx.x;
    if (i < n) row[i] += bs[blockIdx.x];
    if (i == 0) row[n] = E;
}

// per-replica base offsets: posR[r][d] = row[d] + sum_{r'<r} cntR[r'][d]
__global__ __launch_bounds__(256) void bases_k(const int* __restrict__ cntR,
                                               const int* __restrict__ row,
                                               int* __restrict__ posR, int n) {
    int i = blockIdx.x * 256 + threadIdx.x;
    if (i < n) {
        int running = row[i];
#pragma unroll
        for (int r = 0; r < REP; ++r) {
            posR[r * n + i] = running;
            running += cntR[r * n + i];
        }
    }
}

// place each edge; payload = {src, raw weight}
__global__ __launch_bounds__(256) void csr_scatter(const int* __restrict__ ei,
                                                   const float* __restrict__ w,
                                                   int* __restrict__ posR,
                                                   int2* __restrict__ sn,
                                                   int N, int E) {
    int e = blockIdx.x * 256 + threadIdx.x;
    if (e < E) {
        int s = ei[e];
        int d = ei[E + e];
        int r = blockIdx.x & (REP - 1);
        int pos = atomicAdd(posR + r * N + d, 1);
        sn[pos] = make_int2(s, __float_as_int(w[e]));
    }
}

// deg/dinv from CSR: non-atomic segmented sum of weights
__global__ __launch_bounds__(256) void deg_csr(const int2* __restrict__ sn,
                                               const int* __restrict__ row,
                                               float* __restrict__ dinv, int n) {
    int i = blockIdx.x * 256 + threadIdx.x;
    if (i < n) {
        float s = 1.0f;  // self-loop weight
        int pe = row[i + 1];
        for (int p = row[i]; p < pe; ++p) s += __int_as_float(sn[p].y);
        dinv[i] = rsqrtf(fmaxf(s, 1e-12f));
    }
}

// payload.y <- w * dinv[src]
__global__ __launch_bounds__(256) void scale_pay(int2* __restrict__ sn,
                                                 const float* __restrict__ dinv,
                                                 int E) {
    int p = blockIdx.x * 256 + threadIdx.x;
    if (p < E) {
        int2 v = sn[p];
        sn[p] = make_int2(v.x, __float_as_int(__int_as_float(v.y) * dinv[v.x]));
    }
}

// ---------------- fused GCN aggregation (gather, no atomics) ---------
// out[i] = relu( (sum_e pay_e*t[src_e] + t[i]*dinv[i]) * dinv[i] + b )
__global__ __launch_bounds__(256) void gcn_agg(const float* __restrict__ t,
                                               const int2* __restrict__ sn,
                                               const int* __restrict__ row,
                                               const float* __restrict__ dinv,
                                               const float* __restrict__ bias,
                                               float* __restrict__ out, int N) {
    const int lane = threadIdx.x & 63;
    int i = __builtin_amdgcn_readfirstlane((int)(blockIdx.x * 4) + (threadIdx.x >> 6));
    if (i >= N) return;
    float di   = dinv[i];
    float self = t[(size_t)i * 64 + lane];
    float acc  = 0.f;
    int p  = row[i];
    int pe = row[i + 1];
    for (; p + 4 <= pe; p += 4) {
        int2 v0 = sn[p];
        int2 v1 = sn[p + 1];
        int2 v2 = sn[p + 2];
        int2 v3 = sn[p + 3];
        acc += t[(size_t)v0.x * 64 + lane] * __int_as_float(v0.y);
        acc += t[(size_t)v1.x * 64 + lane] * __int_as_float(v1.y);
        acc += t[(size_t)v2.x * 64 + lane] * __int_as_float(v2.y);
        acc += t[(size_t)v3.x * 64 + lane] * __int_as_float(v3.y);
    }
    for (; p < pe; ++p) {
        int2 v = sn[p];
        acc += t[(size_t)v.x * 64 + lane] * __int_as_float(v.y);
    }
    float x = (acc + self * di) * di + bias[lane];
    out[(size_t)i * 64 + lane] = fmaxf(x, 0.f);
}

// =====================================================================
extern "C" void kernel_launch(void* const* d_in, const int* in_sizes, int n_in,
                              void* d_out, int out_size, void* d_ws, size_t ws_size,
                              hipStream_t stream) {
    const float* x      = (const float*)d_in[0];
    const int*   ei     = (const int*)d_in[1];   // int32 per harness contract
    const float* ew     = (const float*)d_in[2];
    const float* enc1_w = (const float*)d_in[3];
    const float* enc1_b = (const float*)d_in[4];
    const float* enc2_w = (const float*)d_in[5];
    const float* enc2_b = (const float*)d_in[6];
    const float* gcn1_w = (const float*)d_in[7];
    const float* gcn1_b = (const float*)d_in[8];
    const float* gcn2_w = (const float*)d_in[9];
    const float* gcn2_b = (const float*)d_in[10];
    const float* dec1_w = (const float*)d_in[11];
    const float* dec1_b = (const float*)d_in[12];
    const float* dec2_w = (const float*)d_in[13];
    const float* dec2_b = (const float*)d_in[14];

    const int N = in_sizes[0] / 256;   // 50000
    const int E = in_sizes[2];         // 1600000

    // workspace (~42 MB):
    //  bufA [N*128]: h1 -> {sn[E] int2 | bufC[N*64]} -> h5
    //  bufB [N*64]: h2/h3/h4 ; dinv[N]; row[N+1]; bs[256]; cntR[8N]; posR[8N]
    float* ws   = (float*)d_ws;
    float* bufA = ws;
    int2*  sn   = (int2*)bufA;                 // E int2 == N*64 floats
    float* bufC = bufA + (size_t)2 * E;        // N*64
    float* bufB = bufA + (size_t)N * 128;      // N*64
    float* dinv = bufB + (size_t)N * 64;       // N
    int*   row  = (int*)(dinv + N);            // N+1
    int*   bs   = row + (N + 1);               // 256
    int*   cntR = bs + 256;                    // 8N
    int*   posR = cntR + (size_t)REP * N;      // 8N

    const int gemmGrid = (N + 127) / 128;      // 391
    const int nBlkN    = (N + 255) / 256;      // 196
    const int nBlkE    = (E + 255) / 256;      // 6250

    // encoder
    gemm_rt<256, 128, 128, 1, true><<<dim3(gemmGrid, 1), 256, 0, stream>>>(
        x, enc1_w, enc1_b, bufA, N);
    gemm_rt<128, 64, 64, 1, true><<<dim3(gemmGrid, 1), 256, 0, stream>>>(
        bufA, enc2_w, enc2_b, bufB, N);

    // CSR build (shared by both GCN layers); bufA dead until dec1
    zero_int<<<(REP * N + 255) / 256, 256, 0, stream>>>(cntR, REP * N);
    hist_k<<<nBlkE, 256, 0, stream>>>(ei, cntR, N, E);
    scan_block<<<nBlkN, 256, 0, stream>>>(cntR, row, bs, N);
    scan_tops<<<1, 256, 0, stream>>>(bs, nBlkN);
    scan_add<<<nBlkN, 256, 0, stream>>>(row, bs, N, E);
    bases_k<<<nBlkN, 256, 0, stream>>>(cntR, row, posR, N);
    csr_scatter<<<nBlkE, 256, 0, stream>>>(ei, ew, posR, sn, N, E);
    deg_csr<<<nBlkN, 256, 0, stream>>>(sn, row, dinv, N);
    scale_pay<<<nBlkE, 256, 0, stream>>>(sn, dinv, E);

    // GCN layer 1
    gemm_rt<64, 64, 64, 0, false><<<dim3(gemmGrid, 1), 256, 0, stream>>>(
        bufB, gcn1_w, nullptr, bufC, N);
    gcn_agg<<<(N + 3) / 4, 256, 0, stream>>>(bufC, sn, row, dinv, gcn1_b, bufB, N);

    // GCN layer 2
    gemm_rt<64, 64, 64, 0, false><<<dim3(gemmGrid, 1), 256, 0, stream>>>(
        bufB, gcn2_w, nullptr, bufC, N);
    gcn_agg<<<(N + 3) / 4, 256, 0, stream>>>(bufC, sn, row, dinv, gcn2_b, bufB, N);

    // decoder
    gemm_rt<64, 128, 128, 1, true><<<dim3(gemmGrid, 1), 256, 0, stream>>>(
        bufB, dec1_w, dec1_b, bufA, N);
    gemm_rt<128, 128, 256, 2, true><<<dim3(gemmGrid, 2), 256, 0, stream>>>(
        bufA, dec2_w, dec2_b, (float*)d_out, N);
}